// Round 3
// baseline (435.260 us; speedup 1.0000x reference)
//
#include <hip/hip_runtime.h>

typedef __bf16 bf16x8 __attribute__((ext_vector_type(8)));
typedef float floatx16 __attribute__((ext_vector_type(16)));

__device__ __forceinline__ unsigned short f2bf(float f) {
    union { float f; unsigned int u; } a;
    a.f = f;
    unsigned int u = a.u;
    unsigned int r = (u + 0x7FFFu + ((u >> 16) & 1u)) >> 16;  // RNE
    return (unsigned short)r;
}

__device__ __forceinline__ float bf2f(unsigned short s) {
    union { unsigned int u; float f; } a;
    a.u = ((unsigned int)s) << 16;
    return a.f;
}

__device__ __forceinline__ void async_copy16(const void* g, void* l) {
    __builtin_amdgcn_global_load_lds(
        (const __attribute__((address_space(1))) unsigned int*)g,
        (__attribute__((address_space(3))) unsigned int*)l,
        16, 0, 0);
}

// Fused prep: [x|h] -> Abf [8192,2048] bf16 and [Wx|Wh] -> Wbf [4096,2048] bf16.
// One thread per 4 output elements; first 16384 blocks do A, rest do W.
__global__ void prep_cat(const float* __restrict__ x, const float* __restrict__ h,
                         const float* __restrict__ Wx, const float* __restrict__ Wh,
                         unsigned short* __restrict__ Abf, unsigned short* __restrict__ Wbf) {
    int T = blockIdx.x * 256 + threadIdx.x;
    const float* a;
    const float* b;
    unsigned short* o;
    size_t e;
    if (T < 4194304) { a = x; b = h; o = Abf; e = (size_t)T * 4; }
    else             { a = Wx; b = Wh; o = Wbf; e = (size_t)(T - 4194304) * 4; }
    int m = (int)(e >> 11);
    int k = (int)(e & 2047);
    const float* src = (k < 1024) ? (a + (size_t)m * 1024 + k)
                                  : (b + (size_t)m * 1024 + (k - 1024));
    float4 v = *(const float4*)src;
    ushort4 u;
    u.x = f2bf(v.x); u.y = f2bf(v.y); u.z = f2bf(v.z); u.w = f2bf(v.w);
    *(ushort4*)(o + e) = u;
}

__device__ __forceinline__ bf16x8 ldfrag(const char* base, int row, int chunk) {
    int c = chunk ^ ((row >> 1) & 3);     // undo XOR staging swizzle
    return *(const bf16x8*)(base + row * 64 + c * 16);
}

// Fused GEMM + LSTM. Block tile: 64 M-rows x 64 H-cols x 4 gates.
// Wave g computes gate g's 64x64 tile with 2x2 mfma_f32_32x32x16_bf16 frags.
// Gates exchanged through LDS (bf16), epilogue applies bias + nonlinearity,
// writes h_new and c directly.
__global__ __launch_bounds__(256) void gemm_lstm(
    const unsigned short* __restrict__ A,     // [8192,2048] bf16
    const unsigned short* __restrict__ W,     // [4096,2048] bf16 (rows: gate*1024+h)
    const float* __restrict__ bx, const float* __restrict__ bh,
    const float* __restrict__ c1,             // [8192,1024] f32
    float* __restrict__ out) {                // h_new [8192,1024] then c [8192,1024]
    __shared__ __align__(16) char smem[32768];
    char* As = smem;            // 64 rows x 64B (32 bf16), XOR chunk swizzle
    char* Ws = smem + 4096;     // 4 gates x 64 rows x 64B

    const int t = threadIdx.x;
    const int lane = t & 63;
    const int wave = t >> 6;                  // = gate index
    const int tileH = blockIdx.x * 64;
    const int tileM = blockIdx.y * 64;
    const int l31 = lane & 31;
    const int half = lane >> 5;

    floatx16 acc[2][2] = {};

    // staging: thread covers row sr (0..63), 16B LDS slot sq; fetches global chunk qg
    const int sr = wave * 16 + (lane >> 2);
    const int sq = lane & 3;
    const int qg = sq ^ ((sr >> 1) & 3);

    const unsigned short* Arow = A + (size_t)(tileM + sr) * 2048 + qg * 8;
    const unsigned short* Wrow = W + (size_t)(tileH + sr) * 2048 + qg * 8;
    char* AsDst = As + wave * 1024;           // HW adds lane*16
    char* WsDst = Ws + wave * 1024;
    const char* Wg = Ws + wave * 4096;        // this wave's gate region

    for (int kt = 0; kt < 2048; kt += 32) {
        async_copy16(Arow + kt, AsDst);
#pragma unroll
        for (int q = 0; q < 4; ++q)           // gate q rows live at W row q*1024 + ...
            async_copy16(Wrow + (size_t)q * 1024 * 2048 + kt, WsDst + q * 4096);
        __syncthreads();

#pragma unroll
        for (int ksub = 0; ksub < 2; ++ksub) {
            int ch = ksub * 2 + half;
            bf16x8 a0 = ldfrag(As, l31, ch);
            bf16x8 a1 = ldfrag(As, 32 + l31, ch);
            bf16x8 b0 = ldfrag(Wg, l31, ch);
            bf16x8 b1 = ldfrag(Wg, 32 + l31, ch);
            acc[0][0] = __builtin_amdgcn_mfma_f32_32x32x16_bf16(a0, b0, acc[0][0], 0, 0, 0);
            acc[0][1] = __builtin_amdgcn_mfma_f32_32x32x16_bf16(a0, b1, acc[0][1], 0, 0, 0);
            acc[1][0] = __builtin_amdgcn_mfma_f32_32x32x16_bf16(a1, b0, acc[1][0], 0, 0, 0);
            acc[1][1] = __builtin_amdgcn_mfma_f32_32x32x16_bf16(a1, b1, acc[1][1], 0, 0, 0);
        }
        __syncthreads();
    }

    // ---- exchange: wave g writes its 64x64 gate tile (bf16) to LDS region g ----
    unsigned short* Exg = (unsigned short*)smem + wave * 4096;
#pragma unroll
    for (int i = 0; i < 2; ++i)
#pragma unroll
        for (int j = 0; j < 2; ++j)
#pragma unroll
            for (int r = 0; r < 16; ++r) {
                int row = i * 32 + (r & 3) + 8 * (r >> 2) + 4 * half;  // m74/m101 C/D map
                int col = j * 32 + l31;
                Exg[row * 64 + col] = f2bf(acc[i][j][r]);
            }
    __syncthreads();

    // ---- epilogue: each thread does 4 rows x 4 cols of the 64x64 cell tile ----
    const unsigned short* E = (const unsigned short*)smem;
    const int col0 = (t & 15) * 4;
    const int row0 = (t >> 4) * 4;

    float4 bi, bff, bo, bc;
    {
        const float* p;
        p = bx + 0 * 1024 + tileH + col0; float4 v0 = *(const float4*)p;
        p = bh + 0 * 1024 + tileH + col0; float4 w0 = *(const float4*)p;
        bi.x = v0.x + w0.x; bi.y = v0.y + w0.y; bi.z = v0.z + w0.z; bi.w = v0.w + w0.w;
        p = bx + 1 * 1024 + tileH + col0; v0 = *(const float4*)p;
        p = bh + 1 * 1024 + tileH + col0; w0 = *(const float4*)p;
        bff.x = v0.x + w0.x; bff.y = v0.y + w0.y; bff.z = v0.z + w0.z; bff.w = v0.w + w0.w;
        p = bx + 2 * 1024 + tileH + col0; v0 = *(const float4*)p;
        p = bh + 2 * 1024 + tileH + col0; w0 = *(const float4*)p;
        bo.x = v0.x + w0.x; bo.y = v0.y + w0.y; bo.z = v0.z + w0.z; bo.w = v0.w + w0.w;
        p = bx + 3 * 1024 + tileH + col0; v0 = *(const float4*)p;
        p = bh + 3 * 1024 + tileH + col0; w0 = *(const float4*)p;
        bc.x = v0.x + w0.x; bc.y = v0.y + w0.y; bc.z = v0.z + w0.z; bc.w = v0.w + w0.w;
    }

#pragma unroll
    for (int v = 0; v < 4; ++v) {
        int row = row0 + v;
        ushort4 gi = *(const ushort4*)(E + 0 * 4096 + row * 64 + col0);
        ushort4 gf = *(const ushort4*)(E + 1 * 4096 + row * 64 + col0);
        ushort4 go = *(const ushort4*)(E + 2 * 4096 + row * 64 + col0);
        ushort4 gc = *(const ushort4*)(E + 3 * 4096 + row * 64 + col0);
        size_t goff = (size_t)(tileM + row) * 1024 + tileH + col0;
        float4 vc1 = *(const float4*)(c1 + goff);

        float4 hn, cc;
        {
            float ii, ff, oo, cb, carg;
            // x
            ii = 1.f / (1.f + __expf(-(bf2f(gi.x) + bi.x)));
            ff = 1.f / (1.f + __expf(-(bf2f(gf.x) + bff.x)));
            oo = 1.f / (1.f + __expf(-(bf2f(go.x) + bo.x)));
            cb = tanhf(bf2f(gc.x) + bc.x);
            carg = ff * vc1.x + ii * cb;
            cc.x = 1.f / (1.f + __expf(-carg));
            hn.x = tanhf(cc.x) * oo;
            // y
            ii = 1.f / (1.f + __expf(-(bf2f(gi.y) + bi.y)));
            ff = 1.f / (1.f + __expf(-(bf2f(gf.y) + bff.y)));
            oo = 1.f / (1.f + __expf(-(bf2f(go.y) + bo.y)));
            cb = tanhf(bf2f(gc.y) + bc.y);
            carg = ff * vc1.y + ii * cb;
            cc.y = 1.f / (1.f + __expf(-carg));
            hn.y = tanhf(cc.y) * oo;
            // z
            ii = 1.f / (1.f + __expf(-(bf2f(gi.z) + bi.z)));
            ff = 1.f / (1.f + __expf(-(bf2f(gf.z) + bff.z)));
            oo = 1.f / (1.f + __expf(-(bf2f(go.z) + bo.z)));
            cb = tanhf(bf2f(gc.z) + bc.z);
            carg = ff * vc1.z + ii * cb;
            cc.z = 1.f / (1.f + __expf(-carg));
            hn.z = tanhf(cc.z) * oo;
            // w
            ii = 1.f / (1.f + __expf(-(bf2f(gi.w) + bi.w)));
            ff = 1.f / (1.f + __expf(-(bf2f(gf.w) + bff.w)));
            oo = 1.f / (1.f + __expf(-(bf2f(go.w) + bo.w)));
            cb = tanhf(bf2f(gc.w) + bc.w);
            carg = ff * vc1.w + ii * cb;
            cc.w = 1.f / (1.f + __expf(-carg));
            hn.w = tanhf(cc.w) * oo;
        }
        *(float4*)(out + goff) = hn;
        *(float4*)(out + 8388608 + goff) = cc;
    }
}

extern "C" void kernel_launch(void* const* d_in, const int* in_sizes, int n_in,
                              void* d_out, int out_size, void* d_ws, size_t ws_size,
                              hipStream_t stream) {
    const float* x  = (const float*)d_in[0];
    const float* h  = (const float*)d_in[1];
    const float* c1 = (const float*)d_in[2];
    const float* Wx = (const float*)d_in[3];
    const float* bx = (const float*)d_in[4];
    const float* Wh = (const float*)d_in[5];
    const float* bh = (const float*)d_in[6];
    float* out = (float*)d_out;

    char* ws = (char*)d_ws;
    unsigned short* Abf = (unsigned short*)(ws);                // 33,554,432 B
    unsigned short* Wbf = (unsigned short*)(ws + 33554432);     // 16,777,216 B

    prep_cat<<<24576, 256, 0, stream>>>(x, h, Wx, Wh, Abf, Wbf);
    dim3 grid(16, 128);   // x: H-tiles, y: M-tiles
    gemm_lstm<<<grid, 256, 0, stream>>>(Abf, Wbf, bx, bh, c1, out);
}

// Round 4
// 338.418 us; speedup vs baseline: 1.2862x; 1.2862x over previous
//
#include <hip/hip_runtime.h>

typedef __bf16 bf16x8 __attribute__((ext_vector_type(8)));
typedef float floatx4 __attribute__((ext_vector_type(4)));

__device__ __forceinline__ unsigned short f2bf(float f) {
    union { float f; unsigned int u; } a;
    a.f = f;
    unsigned int u = a.u;
    unsigned int r = (u + 0x7FFFu + ((u >> 16) & 1u)) >> 16;  // RNE
    return (unsigned short)r;
}

__device__ __forceinline__ float bf2f(unsigned short s) {
    union { unsigned int u; float f; } a;
    a.u = ((unsigned int)s) << 16;
    return a.f;
}

__device__ __forceinline__ void async_copy16(const void* g, void* l) {
    __builtin_amdgcn_global_load_lds(
        (const __attribute__((address_space(1))) unsigned int*)g,
        (__attribute__((address_space(3))) unsigned int*)l,
        16, 0, 0);
}

__device__ __forceinline__ float sigmoidf_fast(float x) {
    return 1.f / (1.f + __expf(-x));
}
__device__ __forceinline__ float tanhf_fast(float x) {
    return 1.f - 2.f / (__expf(2.f * x) + 1.f);   // exact at +-inf, ~ulp of expf else
}

// Prep: [x|h] -> Abf [8192,2048] bf16 (identity rows) and
// [Wx|Wh] -> Wbf [4096,2048] bf16 with ROW PERMUTATION
//   out row n' = hg*128 + gate*32 + hl  <-  src row gate*1024 + hg*32 + hl
// so that a 128-column GEMM N-tile holds all 4 gates for 32 h-values.
__global__ void prep_cat(const float* __restrict__ x, const float* __restrict__ h,
                         const float* __restrict__ Wx, const float* __restrict__ Wh,
                         unsigned short* __restrict__ Abf, unsigned short* __restrict__ Wbf) {
    int T = blockIdx.x * 256 + threadIdx.x;
    const float* a;
    const float* b;
    unsigned short* o;
    size_t e;
    size_t srow;
    if (T < 4194304) {
        e = (size_t)T * 4;
        a = x; b = h; o = Abf;
        srow = e >> 11;
    } else {
        e = (size_t)(T - 4194304) * 4;
        a = Wx; b = Wh; o = Wbf;
        int m = (int)(e >> 11);                 // permuted (output) row
        int hg = m >> 7, gate = (m >> 5) & 3, hl = m & 31;
        srow = (size_t)(gate * 1024 + hg * 32 + hl);
    }
    int k = (int)(e & 2047);
    const float* src = (k < 1024) ? (a + srow * 1024 + k)
                                  : (b + srow * 1024 + (k - 1024));
    float4 v = *(const float4*)src;
    ushort4 u;
    u.x = f2bf(v.x); u.y = f2bf(v.y); u.z = f2bf(v.z); u.w = f2bf(v.w);
    *(ushort4*)(o + e) = u;
}

__device__ __forceinline__ bf16x8 ldfrag(const char* base, int row, int chunk) {
    int c = chunk ^ ((row >> 1) & 3);     // undo XOR staging swizzle
    return *(const bf16x8*)(base + row * 64 + c * 16);
}

// Fused GEMM + LSTM, round-1 GEMM structure (128x128 tile, BK=32, 4 waves of
// 4x4 mfma_f32_16x16x32_bf16). W is gate-interleaved so each block owns
// complete cells; gates exchanged via LDS bf16 (row stride 36 ushorts ->
// conflict-free exchange writes), epilogue applies bias+nonlinearity.
__global__ __launch_bounds__(256) void gemm_lstm(
    const unsigned short* __restrict__ A,     // [8192,2048] bf16
    const unsigned short* __restrict__ W,     // [4096,2048] bf16, gate-interleaved rows
    const float* __restrict__ bx, const float* __restrict__ bh,
    const float* __restrict__ c1,             // [8192,1024] f32
    float* __restrict__ out) {                // h_new [8192,1024] then c [8192,1024]
    __shared__ __align__(16) char smem[36864];   // staging 16KB, then exchange 36KB
    char* As = smem;            // 128 rows x 64 B (32 bf16), XOR chunk swizzle
    char* Bs = smem + 8192;

    const int t = threadIdx.x;
    const int lane = t & 63;
    const int wave = t >> 6;
    const int tileN = blockIdx.x * 128;
    const int tileM = blockIdx.y * 128;
    const int wm = wave & 1;
    const int wn = wave >> 1;
    const int l15 = lane & 15;
    const int quad = lane >> 4;

    floatx4 acc[4][4] = {};

    const int lr = wave * 16 + (lane >> 2);
    const int lq = lane & 3;

    for (int kt = 0; kt < 2048; kt += 32) {
#pragma unroll
        for (int j = 0; j < 2; ++j) {
            int r = j * 64 + lr;
            int qg = lq ^ ((r >> 1) & 3);
            const unsigned short* ga = A + (size_t)(tileM + r) * 2048 + kt + qg * 8;
            async_copy16(ga, As + j * 4096 + wave * 1024);
            const unsigned short* gb = W + (size_t)(tileN + r) * 2048 + kt + qg * 8;
            async_copy16(gb, Bs + j * 4096 + wave * 1024);
        }
        __syncthreads();

        bf16x8 af[4], bf[4];
#pragma unroll
        for (int i = 0; i < 4; ++i)
            af[i] = ldfrag(As, wm * 64 + i * 16 + l15, quad);
#pragma unroll
        for (int j = 0; j < 4; ++j)
            bf[j] = ldfrag(Bs, wn * 64 + j * 16 + l15, quad);
#pragma unroll
        for (int i = 0; i < 4; ++i)
#pragma unroll
            for (int j = 0; j < 4; ++j)
                acc[i][j] = __builtin_amdgcn_mfma_f32_16x16x32_bf16(af[i], bf[j], acc[i][j], 0, 0, 0);
        __syncthreads();
    }

    // ---- exchange: scatter acc (bf16) into E[gate][row][hl], row stride 36 ----
    unsigned short* E = (unsigned short*)smem;
#pragma unroll
    for (int j = 0; j < 4; ++j) {
        int gate = wn * 2 + (j >> 1);
        int hl = (j & 1) * 16 + l15;
        unsigned short* Eg = E + gate * 4608 + hl;   // 4608 = 128*36
#pragma unroll
        for (int i = 0; i < 4; ++i) {
            int row = wm * 64 + i * 16 + quad * 4;   // C/D map: row = quad*4 + reg
#pragma unroll
            for (int v = 0; v < 4; ++v)
                Eg[(row + v) * 36] = f2bf(acc[i][j][v]);
        }
    }
    __syncthreads();

    // ---- epilogue: thread -> fixed h (hl = lane&31), 16 rows ----
    const int hl = lane & 31;
    const int half = lane >> 5;
    const int hg = (tileN >> 2) + hl;                // global h index
    const int rbase = wave * 32 + half * 16;

    const float bi = bx[hg]          + bh[hg];
    const float bf_ = bx[1024 + hg]  + bh[1024 + hg];
    const float bo = bx[2048 + hg]   + bh[2048 + hg];
    const float bc = bx[3072 + hg]   + bh[3072 + hg];

    const unsigned short* Er = E + hl;
#pragma unroll
    for (int k = 0; k < 16; ++k) {
        int r = rbase + k;
        float gi = bf2f(Er[0 * 4608 + r * 36]) + bi;
        float gf = bf2f(Er[1 * 4608 + r * 36]) + bf_;
        float go = bf2f(Er[2 * 4608 + r * 36]) + bo;
        float gc = bf2f(Er[3 * 4608 + r * 36]) + bc;

        size_t goff = (size_t)(tileM + r) * 1024 + hg;
        float c1v = c1[goff];

        float ii = sigmoidf_fast(gi);
        float ff = sigmoidf_fast(gf);
        float oo = sigmoidf_fast(go);
        float cb = tanhf_fast(gc);
        float cc = sigmoidf_fast(ff * c1v + ii * cb);   // reference quirk: sigmoid on cell
        float hn = tanhf_fast(cc) * oo;

        out[goff] = hn;
        out[8388608 + goff] = cc;
    }
}

extern "C" void kernel_launch(void* const* d_in, const int* in_sizes, int n_in,
                              void* d_out, int out_size, void* d_ws, size_t ws_size,
                              hipStream_t stream) {
    const float* x  = (const float*)d_in[0];
    const float* h  = (const float*)d_in[1];
    const float* c1 = (const float*)d_in[2];
    const float* Wx = (const float*)d_in[3];
    const float* bx = (const float*)d_in[4];
    const float* Wh = (const float*)d_in[5];
    const float* bh = (const float*)d_in[6];
    float* out = (float*)d_out;

    char* ws = (char*)d_ws;
    unsigned short* Abf = (unsigned short*)(ws);                // 33,554,432 B
    unsigned short* Wbf = (unsigned short*)(ws + 33554432);     // 16,777,216 B

    prep_cat<<<24576, 256, 0, stream>>>(x, h, Wx, Wh, Abf, Wbf);
    dim3 grid(32, 64);   // x: N-tiles (gate-interleaved cols), y: M-tiles
    gemm_lstm<<<grid, 256, 0, stream>>>(Abf, Wbf, bx, bh, c1, out);
}